// Round 1
// baseline (754.603 us; speedup 1.0000x reference)
//
#include <hip/hip_runtime.h>

#define NN 100000
#define NE 600000
#define F  128

// workspace layout (bytes)
#define OFF_DEG   0            // int[NN]
#define OFF_DINV  (512*1024)   // float[NN]
#define OFF_FLAG  (960*1024)   // int[1]  : 1 if edge_index stored as int64, 0 if int32
#define OFF_G     (1024*1024)  // float[NN*F]

// ---------------------------------------------------------------------------
// Detect whether edge_index buffer is int64 (odd int32 words are all high
// halves == 0 for values in [0, 2^31)) or int32.
__global__ void k_detect(const int* __restrict__ ei, int* __restrict__ flag) {
    __shared__ int cnt;
    if (threadIdx.x == 0) cnt = 0;
    __syncthreads();
    int v = ei[2 * threadIdx.x + 1];
    if (v == 0) atomicAdd(&cnt, 1);
    __syncthreads();
    if (threadIdx.x == 0) *flag = (cnt > 128) ? 1 : 0;
}

// ---------------------------------------------------------------------------
__global__ __launch_bounds__(256) void k_deg(const int* __restrict__ ei,
                                             const int* __restrict__ flag,
                                             int* __restrict__ deg) {
    int e = blockIdx.x * 256 + threadIdx.x;
    if (e < NE) {
        int f = *flag;
        int dst = ei[(NE + e) << f];
        atomicAdd(&deg[dst], 1);
    }
}

__global__ __launch_bounds__(256) void k_dinv(const int* __restrict__ deg,
                                              float* __restrict__ dinv) {
    int i = blockIdx.x * 256 + threadIdx.x;
    if (i < NN) {
        // +1 for the self-loop; deg+1 > 0 always
        dinv[i] = rsqrtf((float)(deg[i] + 1));
    }
}

// ---------------------------------------------------------------------------
// g = (x @ W) * dinv[row]; also out = g  (self-loop contribution; final kernel
// multiplies by dinv[row] again and adds bias).
// Block: 256 threads, tile 128 rows x 128 cols, 8x8 register blocking.
// LDS: xs[128][128] (XOR-swizzled on k by ((r>>3)&3)<<3) + W[128][128] = 128 KB.
__global__ __launch_bounds__(256) void k_gemm(const float* __restrict__ x,
                                              const float* __restrict__ W,
                                              const float* __restrict__ dinv,
                                              float* __restrict__ g,
                                              float* __restrict__ out) {
    extern __shared__ float smem[];
    float* xs = smem;            // 128*128
    float* Wl = smem + 128*128;  // 128*128

    const int tid  = threadIdx.x;
    const int row0 = blockIdx.x * 128;

    // stage W (plain layout), 4096 float4s
    for (int idx = tid; idx < 4096; idx += 256) {
        int k = idx >> 5, kq = idx & 31;
        float4 v = *(const float4*)(W + k * F + 4 * kq);
        *(float4*)(Wl + k * F + 4 * kq) = v;
    }
    // stage x tile transposed-in-place with XOR swizzle: xs[r][m] = x[r][m ^ s(r)]
    for (int idx = tid; idx < 4096; idx += 256) {
        int r = idx >> 5, kq = idx & 31;
        int row = row0 + r;
        float4 v = make_float4(0.f, 0.f, 0.f, 0.f);
        if (row < NN) v = *(const float4*)(x + (long)row * F + 4 * kq);
        int s = ((r >> 3) & 3) << 3;
        *(float4*)(xs + r * F + ((4 * kq) ^ s)) = v;
    }
    __syncthreads();

    const int tr = tid >> 4;        // 0..15 -> rows
    const int tc = tid & 15;        // 0..15 -> cols
    const int r0 = tr * 8;
    const int c0 = tc * 8;
    const int sw = (tr & 3) << 3;   // swizzle for this thread's rows

    float acc[8][8];
#pragma unroll
    for (int j = 0; j < 8; ++j)
#pragma unroll
        for (int c = 0; c < 8; ++c) acc[j][c] = 0.f;

    for (int k = 0; k < 128; ++k) {
        float4 w0 = *(const float4*)(Wl + k * F + c0);
        float4 w1 = *(const float4*)(Wl + k * F + c0 + 4);
        int kx = k ^ sw;
        float xv[8];
#pragma unroll
        for (int j = 0; j < 8; ++j) xv[j] = xs[(r0 + j) * F + kx];
#pragma unroll
        for (int j = 0; j < 8; ++j) {
            acc[j][0] += xv[j] * w0.x; acc[j][1] += xv[j] * w0.y;
            acc[j][2] += xv[j] * w0.z; acc[j][3] += xv[j] * w0.w;
            acc[j][4] += xv[j] * w1.x; acc[j][5] += xv[j] * w1.y;
            acc[j][6] += xv[j] * w1.z; acc[j][7] += xv[j] * w1.w;
        }
    }

#pragma unroll
    for (int j = 0; j < 8; ++j) {
        int row = row0 + r0 + j;
        if (row < NN) {
            float dv = dinv[row];
            float4 a, b4;
            a.x = acc[j][0] * dv; a.y = acc[j][1] * dv;
            a.z = acc[j][2] * dv; a.w = acc[j][3] * dv;
            b4.x = acc[j][4] * dv; b4.y = acc[j][5] * dv;
            b4.z = acc[j][6] * dv; b4.w = acc[j][7] * dv;
            long base = (long)row * F + c0;
            *(float4*)(g + base)       = a;
            *(float4*)(g + base + 4)   = b4;
            *(float4*)(out + base)     = a;
            *(float4*)(out + base + 4) = b4;
        }
    }
}

// ---------------------------------------------------------------------------
// One wave per edge: out[dst][:] += g[src][:]
__global__ __launch_bounds__(256) void k_scatter(const int* __restrict__ ei,
                                                 const int* __restrict__ flag,
                                                 const float* __restrict__ g,
                                                 float* __restrict__ out) {
    int e = blockIdx.x * 4 + (threadIdx.x >> 6);
    int lane = threadIdx.x & 63;
    if (e >= NE) return;
    int f = *flag;
    int src = ei[e << f];
    int dst = ei[(NE + e) << f];
    float2 v = *(const float2*)(g + (long)src * F + lane * 2);
    float* o = out + (long)dst * F + lane * 2;
    atomicAdd(o, v.x);
    atomicAdd(o + 1, v.y);
}

// ---------------------------------------------------------------------------
// out = relu(out * dinv[row] + b)
__global__ __launch_bounds__(256) void k_final(float* __restrict__ out,
                                               const float* __restrict__ dinv,
                                               const float* __restrict__ b) {
    int t = blockIdx.x * 256 + threadIdx.x;   // float4 index
    if (t >= NN * (F / 4)) return;
    int row = t >> 5;
    int c4  = (t & 31) * 4;
    float dv = dinv[row];
    float4 v  = *(float4*)(out + (long)t * 4);
    float4 bb = *(const float4*)(b + c4);
    v.x = fmaxf(v.x * dv + bb.x, 0.f);
    v.y = fmaxf(v.y * dv + bb.y, 0.f);
    v.z = fmaxf(v.z * dv + bb.z, 0.f);
    v.w = fmaxf(v.w * dv + bb.w, 0.f);
    *(float4*)(out + (long)t * 4) = v;
}

// ---------------------------------------------------------------------------
extern "C" void kernel_launch(void* const* d_in, const int* in_sizes, int n_in,
                              void* d_out, int out_size, void* d_ws, size_t ws_size,
                              hipStream_t stream) {
    const float* x  = (const float*)d_in[0];
    const float* W  = (const float*)d_in[1];
    const float* b  = (const float*)d_in[2];
    const int*   ei = (const int*)d_in[3];
    float* out = (float*)d_out;

    char* ws = (char*)d_ws;
    int*   deg  = (int*)(ws + OFF_DEG);
    float* dinv = (float*)(ws + OFF_DINV);
    int*   flag = (int*)(ws + OFF_FLAG);
    float* g    = (float*)(ws + OFF_G);

    hipMemsetAsync(deg, 0, NN * sizeof(int), stream);
    k_detect<<<1, 256, 0, stream>>>(ei, flag);
    k_deg<<<(NE + 255) / 256, 256, 0, stream>>>(ei, flag, deg);
    k_dinv<<<(NN + 255) / 256, 256, 0, stream>>>(deg, dinv);

    hipFuncSetAttribute(reinterpret_cast<const void*>(k_gemm),
                        hipFuncAttributeMaxDynamicSharedMemorySize, 131072);
    k_gemm<<<dim3((NN + 127) / 128, 1, 1), 256, 131072, stream>>>(x, W, dinv, g, out);

    k_scatter<<<NE / 4, 256, 0, stream>>>(ei, flag, g, out);
    k_final<<<(NN * (F / 4) + 255) / 256, 256, 0, stream>>>(out, dinv, b);
}

// Round 2
// 383.135 us; speedup vs baseline: 1.9695x; 1.9695x over previous
//
#include <hip/hip_runtime.h>

#define NN 100000
#define NE 600000
#define F  128

// workspace layout (bytes)
#define OFF_DEG    0              // int[NN]            (destroyed by k_fill)
#define OFF_DINV   (512*1024)     // float[NN]
#define OFF_FLAG   (960*1024)     // int[1]
#define OFF_SEG    (964*1024)     // int[1024] segment sums / offsets
#define OFF_ROWPTR (1024*1024)    // int[NN+1]
#define OFF_CSR    (1536*1024)    // int[NE]
#define OFF_G      (4096*1024)    // float[NN*F]  (51.2 MB)
// total ~55.3 MB

#define SCAN_T 1024
#define SCAN_CH 98   // 1024*98 >= 100000

// ---------------------------------------------------------------------------
__global__ void k_detect(const int* __restrict__ ei, int* __restrict__ flag) {
    __shared__ int cnt;
    if (threadIdx.x == 0) cnt = 0;
    __syncthreads();
    int v = ei[2 * threadIdx.x + 1];
    if (v == 0) atomicAdd(&cnt, 1);
    __syncthreads();
    if (threadIdx.x == 0) *flag = (cnt > 128) ? 1 : 0;
}

__global__ __launch_bounds__(256) void k_deg(const int* __restrict__ ei,
                                             const int* __restrict__ flag,
                                             int* __restrict__ deg) {
    int e = blockIdx.x * 256 + threadIdx.x;
    if (e < NE) {
        int f = *flag;
        int dst = ei[(NE + e) << f];
        atomicAdd(&deg[dst], 1);
    }
}

__global__ __launch_bounds__(256) void k_dinv(const int* __restrict__ deg,
                                              float* __restrict__ dinv) {
    int i = blockIdx.x * 256 + threadIdx.x;
    if (i < NN) dinv[i] = rsqrtf((float)(deg[i] + 1));  // +1 self-loop
}

// ---------------------------------------------------------------------------
// prefix sum of deg -> rowptr (exclusive), rowptr[NN] = NE
__global__ __launch_bounds__(256) void k_scan1(const int* __restrict__ deg,
                                               int* __restrict__ seg) {
    int t = blockIdx.x * 256 + threadIdx.x;
    if (t >= SCAN_T) return;
    int lo = t * SCAN_CH, hi = min(lo + SCAN_CH, NN);
    int s = 0;
    for (int i = lo; i < hi; ++i) s += deg[i];
    seg[t] = s;
}

__global__ __launch_bounds__(SCAN_T) void k_scan2(int* __restrict__ seg) {
    __shared__ int s[SCAN_T];
    int t = threadIdx.x;
    int v = seg[t];
    s[t] = v;
    __syncthreads();
    for (int off = 1; off < SCAN_T; off <<= 1) {
        int u = (t >= off) ? s[t - off] : 0;
        __syncthreads();
        s[t] += u;
        __syncthreads();
    }
    seg[t] = s[t] - v;  // exclusive
}

__global__ __launch_bounds__(256) void k_scan3(const int* __restrict__ deg,
                                               const int* __restrict__ seg,
                                               int* __restrict__ rowptr) {
    int t = blockIdx.x * 256 + threadIdx.x;
    if (t >= SCAN_T) return;
    int lo = t * SCAN_CH, hi = min(lo + SCAN_CH, NN);
    int base = seg[t];
    for (int i = lo; i < hi; ++i) {
        rowptr[i] = base;
        base += deg[i];
    }
    if (t == 0) rowptr[NN] = NE;
}

// ---------------------------------------------------------------------------
// csr[rowptr[dst] + k] = src, using deg as a down-counting cursor
__global__ __launch_bounds__(256) void k_fill(const int* __restrict__ ei,
                                              const int* __restrict__ flag,
                                              const int* __restrict__ rowptr,
                                              int* __restrict__ deg,
                                              int* __restrict__ csr) {
    int e = blockIdx.x * 256 + threadIdx.x;
    if (e >= NE) return;
    int f = *flag;
    int src = ei[e << f];
    int dst = ei[(NE + e) << f];
    int old = atomicSub(&deg[dst], 1);
    csr[rowptr[dst] + old - 1] = src;
}

// ---------------------------------------------------------------------------
// g = (x @ W) * dinv[row]
__global__ __launch_bounds__(256) void k_gemm(const float* __restrict__ x,
                                              const float* __restrict__ W,
                                              const float* __restrict__ dinv,
                                              float* __restrict__ g) {
    extern __shared__ float smem[];
    float* xs = smem;            // 128*128, XOR-swizzled
    float* Wl = smem + 128*128;  // 128*128

    const int tid  = threadIdx.x;
    const int row0 = blockIdx.x * 128;

    for (int idx = tid; idx < 4096; idx += 256) {
        int k = idx >> 5, kq = idx & 31;
        *(float4*)(Wl + k * F + 4 * kq) = *(const float4*)(W + k * F + 4 * kq);
    }
    for (int idx = tid; idx < 4096; idx += 256) {
        int r = idx >> 5, kq = idx & 31;
        int row = row0 + r;
        float4 v = make_float4(0.f, 0.f, 0.f, 0.f);
        if (row < NN) v = *(const float4*)(x + (long)row * F + 4 * kq);
        int s = ((r >> 3) & 3) << 3;
        *(float4*)(xs + r * F + ((4 * kq) ^ s)) = v;
    }
    __syncthreads();

    const int tr = tid >> 4;
    const int tc = tid & 15;
    const int r0 = tr * 8;
    const int c0 = tc * 8;
    const int sw = (tr & 3) << 3;

    float acc[8][8];
#pragma unroll
    for (int j = 0; j < 8; ++j)
#pragma unroll
        for (int c = 0; c < 8; ++c) acc[j][c] = 0.f;

    for (int k = 0; k < 128; ++k) {
        float4 w0 = *(const float4*)(Wl + k * F + c0);
        float4 w1 = *(const float4*)(Wl + k * F + c0 + 4);
        int kx = k ^ sw;
        float xv[8];
#pragma unroll
        for (int j = 0; j < 8; ++j) xv[j] = xs[(r0 + j) * F + kx];
#pragma unroll
        for (int j = 0; j < 8; ++j) {
            acc[j][0] += xv[j] * w0.x; acc[j][1] += xv[j] * w0.y;
            acc[j][2] += xv[j] * w0.z; acc[j][3] += xv[j] * w0.w;
            acc[j][4] += xv[j] * w1.x; acc[j][5] += xv[j] * w1.y;
            acc[j][6] += xv[j] * w1.z; acc[j][7] += xv[j] * w1.w;
        }
    }

#pragma unroll
    for (int j = 0; j < 8; ++j) {
        int row = row0 + r0 + j;
        if (row < NN) {
            float dv = dinv[row];
            float4 a, b4;
            a.x = acc[j][0] * dv; a.y = acc[j][1] * dv;
            a.z = acc[j][2] * dv; a.w = acc[j][3] * dv;
            b4.x = acc[j][4] * dv; b4.y = acc[j][5] * dv;
            b4.z = acc[j][6] * dv; b4.w = acc[j][7] * dv;
            long base = (long)row * F + c0;
            *(float4*)(g + base)     = a;
            *(float4*)(g + base + 4) = b4;
        }
    }
}

// ---------------------------------------------------------------------------
// one wave per node: out[n] = relu((g[n] + sum_{e: dst=n} g[src]) * dinv[n] + b)
__global__ __launch_bounds__(256) void k_gather(const int* __restrict__ rowptr,
                                                const int* __restrict__ csr,
                                                const float* __restrict__ g,
                                                const float* __restrict__ dinv,
                                                const float* __restrict__ b,
                                                float* __restrict__ out) {
    int n = blockIdx.x * 4 + (threadIdx.x >> 6);
    if (n >= NN) return;
    int lane = threadIdx.x & 63;

    float2 acc = *(const float2*)(g + (long)n * F + lane * 2);  // self-loop
    int p0 = rowptr[n], p1 = rowptr[n + 1];
    for (int p = p0; p < p1; ++p) {
        int src = csr[p];
        float2 v = *(const float2*)(g + (long)src * F + lane * 2);
        acc.x += v.x;
        acc.y += v.y;
    }
    float dv = dinv[n];
    float2 bb = *(const float2*)(b + lane * 2);
    float2 o;
    o.x = fmaxf(acc.x * dv + bb.x, 0.f);
    o.y = fmaxf(acc.y * dv + bb.y, 0.f);
    *(float2*)(out + (long)n * F + lane * 2) = o;
}

// ---------------------------------------------------------------------------
extern "C" void kernel_launch(void* const* d_in, const int* in_sizes, int n_in,
                              void* d_out, int out_size, void* d_ws, size_t ws_size,
                              hipStream_t stream) {
    const float* x  = (const float*)d_in[0];
    const float* W  = (const float*)d_in[1];
    const float* b  = (const float*)d_in[2];
    const int*   ei = (const int*)d_in[3];
    float* out = (float*)d_out;

    char* ws = (char*)d_ws;
    int*   deg    = (int*)(ws + OFF_DEG);
    float* dinv   = (float*)(ws + OFF_DINV);
    int*   flag   = (int*)(ws + OFF_FLAG);
    int*   seg    = (int*)(ws + OFF_SEG);
    int*   rowptr = (int*)(ws + OFF_ROWPTR);
    int*   csr    = (int*)(ws + OFF_CSR);
    float* g      = (float*)(ws + OFF_G);

    hipMemsetAsync(deg, 0, NN * sizeof(int), stream);
    k_detect<<<1, 256, 0, stream>>>(ei, flag);
    k_deg<<<(NE + 255) / 256, 256, 0, stream>>>(ei, flag, deg);
    k_dinv<<<(NN + 255) / 256, 256, 0, stream>>>(deg, dinv);

    k_scan1<<<SCAN_T / 256, 256, 0, stream>>>(deg, seg);
    k_scan2<<<1, SCAN_T, 0, stream>>>(seg);
    k_scan3<<<SCAN_T / 256, 256, 0, stream>>>(deg, seg, rowptr);
    k_fill<<<(NE + 255) / 256, 256, 0, stream>>>(ei, flag, rowptr, deg, csr);

    hipFuncSetAttribute(reinterpret_cast<const void*>(k_gemm),
                        hipFuncAttributeMaxDynamicSharedMemorySize, 131072);
    k_gemm<<<dim3((NN + 127) / 128, 1, 1), 256, 131072, stream>>>(x, W, dinv, g);

    k_gather<<<(NN + 3) / 4, 256, 0, stream>>>(rowptr, csr, g, dinv, b, out);
}

// Round 3
// 335.953 us; speedup vs baseline: 2.2462x; 1.1404x over previous
//
#include <hip/hip_runtime.h>

#define NN 100000
#define NE 600000
#define F  128

// workspace layout (bytes)
#define OFF_DEG    0              // int[NN]            (destroyed by k_fill)
#define OFF_DINV   (512*1024)     // float[NN]
#define OFF_FLAG   (960*1024)     // int[1]
#define OFF_SEG    (964*1024)     // int[1024] segment sums / offsets
#define OFF_ROWPTR (1024*1024)    // int[NN+1]
#define OFF_CSR    (1536*1024)    // int[NE]
#define OFF_G      (4096*1024)    // float[NN*F]  (51.2 MB)

#define SCAN_T 1024
#define SCAN_CH 98   // 1024*98 >= 100000

// ---------------------------------------------------------------------------
__global__ void k_detect(const int* __restrict__ ei, int* __restrict__ flag) {
    __shared__ int cnt;
    if (threadIdx.x == 0) cnt = 0;
    __syncthreads();
    int v = ei[2 * threadIdx.x + 1];
    if (v == 0) atomicAdd(&cnt, 1);
    __syncthreads();
    if (threadIdx.x == 0) *flag = (cnt > 128) ? 1 : 0;
}

__global__ __launch_bounds__(256) void k_deg(const int* __restrict__ ei,
                                             const int* __restrict__ flag,
                                             int* __restrict__ deg) {
    int e = blockIdx.x * 256 + threadIdx.x;
    if (e < NE) {
        int f = *flag;
        int dst = ei[(NE + e) << f];
        atomicAdd(&deg[dst], 1);
    }
}

__global__ __launch_bounds__(256) void k_dinv(const int* __restrict__ deg,
                                              float* __restrict__ dinv) {
    int i = blockIdx.x * 256 + threadIdx.x;
    if (i < NN) dinv[i] = rsqrtf((float)(deg[i] + 1));  // +1 self-loop
}

// ---------------------------------------------------------------------------
// prefix sum of deg -> rowptr (exclusive), rowptr[NN] = NE
__global__ __launch_bounds__(256) void k_scan1(const int* __restrict__ deg,
                                               int* __restrict__ seg) {
    int t = blockIdx.x * 256 + threadIdx.x;
    if (t >= SCAN_T) return;
    int lo = t * SCAN_CH, hi = min(lo + SCAN_CH, NN);
    int s = 0;
    for (int i = lo; i < hi; ++i) s += deg[i];
    seg[t] = s;
}

__global__ __launch_bounds__(SCAN_T) void k_scan2(int* __restrict__ seg) {
    __shared__ int s[SCAN_T];
    int t = threadIdx.x;
    int v = seg[t];
    s[t] = v;
    __syncthreads();
    for (int off = 1; off < SCAN_T; off <<= 1) {
        int u = (t >= off) ? s[t - off] : 0;
        __syncthreads();
        s[t] += u;
        __syncthreads();
    }
    seg[t] = s[t] - v;  // exclusive
}

__global__ __launch_bounds__(256) void k_scan3(const int* __restrict__ deg,
                                               const int* __restrict__ seg,
                                               int* __restrict__ rowptr) {
    int t = blockIdx.x * 256 + threadIdx.x;
    if (t >= SCAN_T) return;
    int lo = t * SCAN_CH, hi = min(lo + SCAN_CH, NN);
    int base = seg[t];
    for (int i = lo; i < hi; ++i) {
        rowptr[i] = base;
        base += deg[i];
    }
    if (t == 0) rowptr[NN] = NE;
}

// ---------------------------------------------------------------------------
// csr[rowptr[dst] + k] = src, using deg as a down-counting cursor
__global__ __launch_bounds__(256) void k_fill(const int* __restrict__ ei,
                                              const int* __restrict__ flag,
                                              const int* __restrict__ rowptr,
                                              int* __restrict__ deg,
                                              int* __restrict__ csr) {
    int e = blockIdx.x * 256 + threadIdx.x;
    if (e >= NE) return;
    int f = *flag;
    int src = ei[e << f];
    int dst = ei[(NE + e) << f];
    int old = atomicSub(&deg[dst], 1);
    csr[rowptr[dst] + old - 1] = src;
}

// ---------------------------------------------------------------------------
// g = (x @ W) * dinv[row]
// Tile: 64 rows x 128 cols, BK=32. LDS = xs[64][33] + Wl[32][128] = 24.8 KB
// -> 6 blocks/CU (vs 1 at 128 KB in R2 — occupancy was the measured bottleneck).
// xs padded +1: x-read banks = (4*tr + j + k) % 32, 4 distinct -> conflict-free.
#define BM 64
#define BK 32
__global__ __launch_bounds__(256) void k_gemm(const float* __restrict__ x,
                                              const float* __restrict__ W,
                                              const float* __restrict__ dinv,
                                              float* __restrict__ g) {
    __shared__ float xs[BM][BK + 1];
    __shared__ float Wl[BK][F];

    const int tid  = threadIdx.x;
    const int row0 = blockIdx.x * BM;
    const int tr = tid >> 4;       // 0..15 -> 4 rows each
    const int tc = tid & 15;       // 0..15 -> 8 cols each
    const int r0 = tr * 4;
    const int c0 = tc * 8;

    float acc[4][8];
#pragma unroll
    for (int j = 0; j < 4; ++j)
#pragma unroll
        for (int c = 0; c < 8; ++c) acc[j][c] = 0.f;

    for (int kc = 0; kc < F; kc += BK) {
        // stage x tile: 64 rows x 32 k = 512 float4s, 2 per thread
        for (int i = tid; i < BM * (BK / 4); i += 256) {
            int m  = i >> 3;       // 0..63
            int kq = i & 7;        // 0..7
            int row = row0 + m;
            float4 v = make_float4(0.f, 0.f, 0.f, 0.f);
            if (row < NN) v = *(const float4*)(x + (long)row * F + kc + 4 * kq);
            float* p = &xs[m][4 * kq];
            p[0] = v.x; p[1] = v.y; p[2] = v.z; p[3] = v.w;
        }
        // stage W chunk: 32 x 128 = 1024 float4s, 4 per thread
        for (int i = tid; i < BK * (F / 4); i += 256) {
            int kk = i >> 5;       // 0..31
            int cq = i & 31;       // 0..31
            *(float4*)(&Wl[kk][4 * cq]) =
                *(const float4*)(W + (long)(kc + kk) * F + 4 * cq);
        }
        __syncthreads();

#pragma unroll
        for (int k = 0; k < BK; ++k) {
            float4 w0 = *(const float4*)(&Wl[k][c0]);
            float4 w1 = *(const float4*)(&Wl[k][c0 + 4]);
            float xv[4];
#pragma unroll
            for (int j = 0; j < 4; ++j) xv[j] = xs[r0 + j][k];
#pragma unroll
            for (int j = 0; j < 4; ++j) {
                acc[j][0] += xv[j] * w0.x; acc[j][1] += xv[j] * w0.y;
                acc[j][2] += xv[j] * w0.z; acc[j][3] += xv[j] * w0.w;
                acc[j][4] += xv[j] * w1.x; acc[j][5] += xv[j] * w1.y;
                acc[j][6] += xv[j] * w1.z; acc[j][7] += xv[j] * w1.w;
            }
        }
        __syncthreads();
    }

#pragma unroll
    for (int j = 0; j < 4; ++j) {
        int row = row0 + r0 + j;
        if (row < NN) {
            float dv = dinv[row];
            float4 a, b4;
            a.x  = acc[j][0] * dv; a.y  = acc[j][1] * dv;
            a.z  = acc[j][2] * dv; a.w  = acc[j][3] * dv;
            b4.x = acc[j][4] * dv; b4.y = acc[j][5] * dv;
            b4.z = acc[j][6] * dv; b4.w = acc[j][7] * dv;
            long base = (long)row * F + c0;
            *(float4*)(g + base)     = a;
            *(float4*)(g + base + 4) = b4;
        }
    }
}

// ---------------------------------------------------------------------------
// one wave per node: out[n] = relu((g[n] + sum_{e: dst=n} g[src]) * dinv[n] + b)
__global__ __launch_bounds__(256) void k_gather(const int* __restrict__ rowptr,
                                                const int* __restrict__ csr,
                                                const float* __restrict__ g,
                                                const float* __restrict__ dinv,
                                                const float* __restrict__ b,
                                                float* __restrict__ out) {
    int n = blockIdx.x * 4 + (threadIdx.x >> 6);
    if (n >= NN) return;
    int lane = threadIdx.x & 63;

    float2 acc = *(const float2*)(g + (long)n * F + lane * 2);  // self-loop
    int p0 = rowptr[n], p1 = rowptr[n + 1];
    for (int p = p0; p < p1; ++p) {
        int src = csr[p];
        float2 v = *(const float2*)(g + (long)src * F + lane * 2);
        acc.x += v.x;
        acc.y += v.y;
    }
    float dv = dinv[n];
    float2 bb = *(const float2*)(b + lane * 2);
    float2 o;
    o.x = fmaxf(acc.x * dv + bb.x, 0.f);
    o.y = fmaxf(acc.y * dv + bb.y, 0.f);
    *(float2*)(out + (long)n * F + lane * 2) = o;
}

// ---------------------------------------------------------------------------
extern "C" void kernel_launch(void* const* d_in, const int* in_sizes, int n_in,
                              void* d_out, int out_size, void* d_ws, size_t ws_size,
                              hipStream_t stream) {
    const float* x  = (const float*)d_in[0];
    const float* W  = (const float*)d_in[1];
    const float* b  = (const float*)d_in[2];
    const int*   ei = (const int*)d_in[3];
    float* out = (float*)d_out;

    char* ws = (char*)d_ws;
    int*   deg    = (int*)(ws + OFF_DEG);
    float* dinv   = (float*)(ws + OFF_DINV);
    int*   flag   = (int*)(ws + OFF_FLAG);
    int*   seg    = (int*)(ws + OFF_SEG);
    int*   rowptr = (int*)(ws + OFF_ROWPTR);
    int*   csr    = (int*)(ws + OFF_CSR);
    float* g      = (float*)(ws + OFF_G);

    hipMemsetAsync(deg, 0, NN * sizeof(int), stream);
    k_detect<<<1, 256, 0, stream>>>(ei, flag);
    k_deg<<<(NE + 255) / 256, 256, 0, stream>>>(ei, flag, deg);
    k_dinv<<<(NN + 255) / 256, 256, 0, stream>>>(deg, dinv);

    k_scan1<<<SCAN_T / 256, 256, 0, stream>>>(deg, seg);
    k_scan2<<<1, SCAN_T, 0, stream>>>(seg);
    k_scan3<<<SCAN_T / 256, 256, 0, stream>>>(deg, seg, rowptr);
    k_fill<<<(NE + 255) / 256, 256, 0, stream>>>(ei, flag, rowptr, deg, csr);

    k_gemm<<<(NN + BM - 1) / BM, 256, 0, stream>>>(x, W, dinv, g);

    k_gather<<<(NN + 3) / 4, 256, 0, stream>>>(rowptr, csr, g, dinv, b, out);
}

// Round 4
// 311.597 us; speedup vs baseline: 2.4217x; 1.0782x over previous
//
#include <hip/hip_runtime.h>

#define NN 100000
#define NE 600000
#define F  128

// workspace layout (bytes)
#define OFF_DEG    0              // int[NN]            (destroyed by k_fill)
#define OFF_DINV   (512*1024)     // float[NN]
#define OFF_FLAG   (960*1024)     // int[1]
#define OFF_SEG    (964*1024)     // int[1024]
#define OFF_ROWPTR (1024*1024)    // int[NN+1]
#define OFF_CSR    (1536*1024)    // int[NE]  (2.4 MB)
#define OFF_WT     (3968*1024)    // ushort[F*F]  W^T in bf16 (32 KB)
#define OFF_G      (4096*1024)    // ushort[NN*F] g in bf16 (25.6 MB)

#define SCAN_T 1024
#define SCAN_CH 98   // 1024*98 >= 100000

typedef __attribute__((ext_vector_type(8))) short bf16x8;
typedef __attribute__((ext_vector_type(16))) float f32x16;

__device__ inline unsigned short f2b(float f) {  // fp32 -> bf16 RNE
    unsigned int u = __builtin_bit_cast(unsigned int, f);
    u += 0x7fffu + ((u >> 16) & 1u);
    return (unsigned short)(u >> 16);
}
__device__ inline float b2f_bits(unsigned int hi_bits) {
    return __builtin_bit_cast(float, hi_bits);
}

// ---------------------------------------------------------------------------
__global__ void k_detect(const int* __restrict__ ei, int* __restrict__ flag) {
    __shared__ int cnt;
    if (threadIdx.x == 0) cnt = 0;
    __syncthreads();
    int v = ei[2 * threadIdx.x + 1];
    if (v == 0) atomicAdd(&cnt, 1);
    __syncthreads();
    if (threadIdx.x == 0) *flag = (cnt > 128) ? 1 : 0;
}

__global__ __launch_bounds__(256) void k_deg(const int* __restrict__ ei,
                                             const int* __restrict__ flag,
                                             int* __restrict__ deg) {
    int e = blockIdx.x * 256 + threadIdx.x;
    if (e < NE) {
        int f = *flag;
        int dst = ei[(NE + e) << f];
        atomicAdd(&deg[dst], 1);
    }
}

__global__ __launch_bounds__(256) void k_dinv(const int* __restrict__ deg,
                                              float* __restrict__ dinv) {
    int i = blockIdx.x * 256 + threadIdx.x;
    if (i < NN) dinv[i] = rsqrtf((float)(deg[i] + 1));  // +1 self-loop
}

// ---------------------------------------------------------------------------
__global__ __launch_bounds__(256) void k_scan1(const int* __restrict__ deg,
                                               int* __restrict__ seg) {
    int t = blockIdx.x * 256 + threadIdx.x;
    if (t >= SCAN_T) return;
    int lo = t * SCAN_CH, hi = min(lo + SCAN_CH, NN);
    int s = 0;
    for (int i = lo; i < hi; ++i) s += deg[i];
    seg[t] = s;
}

__global__ __launch_bounds__(SCAN_T) void k_scan2(int* __restrict__ seg) {
    __shared__ int s[SCAN_T];
    int t = threadIdx.x;
    int v = seg[t];
    s[t] = v;
    __syncthreads();
    for (int off = 1; off < SCAN_T; off <<= 1) {
        int u = (t >= off) ? s[t - off] : 0;
        __syncthreads();
        s[t] += u;
        __syncthreads();
    }
    seg[t] = s[t] - v;  // exclusive
}

__global__ __launch_bounds__(256) void k_scan3(const int* __restrict__ deg,
                                               const int* __restrict__ seg,
                                               int* __restrict__ rowptr) {
    int t = blockIdx.x * 256 + threadIdx.x;
    if (t >= SCAN_T) return;
    int lo = t * SCAN_CH, hi = min(lo + SCAN_CH, NN);
    int base = seg[t];
    for (int i = lo; i < hi; ++i) {
        rowptr[i] = base;
        base += deg[i];
    }
    if (t == 0) rowptr[NN] = NE;
}

// ---------------------------------------------------------------------------
__global__ __launch_bounds__(256) void k_fill(const int* __restrict__ ei,
                                              const int* __restrict__ flag,
                                              const int* __restrict__ rowptr,
                                              int* __restrict__ deg,
                                              int* __restrict__ csr) {
    int e = blockIdx.x * 256 + threadIdx.x;
    if (e >= NE) return;
    int f = *flag;
    int src = ei[e << f];
    int dst = ei[(NE + e) << f];
    int old = atomicSub(&deg[dst], 1);
    csr[rowptr[dst] + old - 1] = src;
}

// ---------------------------------------------------------------------------
// Wt[n][k] = bf16(W[k][n])  (one-time transpose+convert, 16384 elems)
__global__ __launch_bounds__(256) void k_wprep(const float* __restrict__ W,
                                               unsigned short* __restrict__ wtg) {
    int idx = blockIdx.x * 256 + threadIdx.x;
    if (idx >= F * F) return;
    int k = idx >> 7, n = idx & 127;
    wtg[n * F + k] = f2b(W[k * F + n]);
}

// ---------------------------------------------------------------------------
// g = bf16( (x @ W) * dinv[row] )  via bf16 MFMA 32x32x16.
// Block: 256 thr = 4 waves; tile 128 rows x 128 cols, K=128 in 8 chunks.
// LDS rows padded to 136 bf16 (272 B) to keep ds_read_b128 16B-aligned.
#define XS_LD 136
__global__ __launch_bounds__(256) void k_gemm(const float* __restrict__ x,
                                              const unsigned short* __restrict__ wtg,
                                              const float* __restrict__ dinv,
                                              unsigned short* __restrict__ gb) {
    extern __shared__ unsigned short smem[];
    unsigned short* xs = smem;                 // [128][136]
    unsigned short* wt = smem + 128 * XS_LD;   // [128][136]

    const int tid  = threadIdx.x;
    const int row0 = blockIdx.x * 128;

    // stage x (fp32 -> bf16): 4096 float4 loads, 16/thread
    for (int i = tid; i < 128 * 32; i += 256) {
        int r = i >> 5, kq = i & 31;
        int row = row0 + r;
        float4 v = make_float4(0.f, 0.f, 0.f, 0.f);
        if (row < NN) v = *(const float4*)(x + (long)row * F + 4 * kq);
        ushort4 h;
        h.x = f2b(v.x); h.y = f2b(v.y); h.z = f2b(v.z); h.w = f2b(v.w);
        *(ushort4*)(xs + r * XS_LD + 4 * kq) = h;
    }
    // stage Wt: 2048 16B copies, 8/thread
    for (int i = tid; i < 128 * 16; i += 256) {
        int r = i >> 4, seg = i & 15;
        *(uint4*)(wt + r * XS_LD + seg * 8) = *(const uint4*)(wtg + r * F + seg * 8);
    }
    __syncthreads();

    const int w    = tid >> 6;      // wave -> rows 32w..32w+31
    const int lane = tid & 63;
    const int m    = lane & 31;
    const int half = lane >> 5;

    f32x16 acc[4];
#pragma unroll
    for (int t = 0; t < 4; ++t)
#pragma unroll
        for (int j = 0; j < 16; ++j) acc[t][j] = 0.f;

    const unsigned short* xrow = xs + (32 * w + m) * XS_LD;
#pragma unroll
    for (int kc = 0; kc < 8; ++kc) {
        bf16x8 a = *(const bf16x8*)(xrow + kc * 16 + half * 8);
#pragma unroll
        for (int nt = 0; nt < 4; ++nt) {
            bf16x8 bfr = *(const bf16x8*)(wt + (nt * 32 + m) * XS_LD + kc * 16 + half * 8);
            acc[nt] = __builtin_amdgcn_mfma_f32_32x32x16_bf16(a, bfr, acc[nt], 0, 0, 0);
        }
    }

    // epilogue: C/D row = (reg&3)+8*(reg>>2)+4*half, col = m
    const int rbase = 32 * w + 4 * half;
    float dv[16];
#pragma unroll
    for (int reg = 0; reg < 16; ++reg) {
        int grow = row0 + rbase + (reg & 3) + 8 * (reg >> 2);
        dv[reg] = (grow < NN) ? dinv[grow] : 0.f;
    }
#pragma unroll
    for (int nt = 0; nt < 4; ++nt) {
#pragma unroll
        for (int reg = 0; reg < 16; ++reg) {
            int grow = row0 + rbase + (reg & 3) + 8 * (reg >> 2);
            if (grow < NN)
                gb[(long)grow * F + nt * 32 + m] = f2b(acc[nt][reg] * dv[reg]);
        }
    }
}

// ---------------------------------------------------------------------------
// one wave per node: out[n] = relu((g[n] + sum_{e: dst=n} g[src]) * dinv[n] + b)
// g is bf16: each lane owns 2 cols via one 4B load per row.
__global__ __launch_bounds__(256) void k_gather(const int* __restrict__ rowptr,
                                                const int* __restrict__ csr,
                                                const unsigned short* __restrict__ gb,
                                                const float* __restrict__ dinv,
                                                const float* __restrict__ b,
                                                float* __restrict__ out) {
    int n = blockIdx.x * 4 + (threadIdx.x >> 6);
    if (n >= NN) return;
    int lane = threadIdx.x & 63;

    unsigned int v = *(const unsigned int*)(gb + (long)n * F + lane * 2);
    float ax = b2f_bits(v << 16);            // col 2*lane
    float ay = b2f_bits(v & 0xffff0000u);    // col 2*lane+1
    int p0 = rowptr[n], p1 = rowptr[n + 1];
    for (int p = p0; p < p1; ++p) {
        int src = csr[p];
        unsigned int u = *(const unsigned int*)(gb + (long)src * F + lane * 2);
        ax += b2f_bits(u << 16);
        ay += b2f_bits(u & 0xffff0000u);
    }
    float dv = dinv[n];
    float2 bb = *(const float2*)(b + lane * 2);
    float2 o;
    o.x = fmaxf(ax * dv + bb.x, 0.f);
    o.y = fmaxf(ay * dv + bb.y, 0.f);
    *(float2*)(out + (long)n * F + lane * 2) = o;
}

// ---------------------------------------------------------------------------
extern "C" void kernel_launch(void* const* d_in, const int* in_sizes, int n_in,
                              void* d_out, int out_size, void* d_ws, size_t ws_size,
                              hipStream_t stream) {
    const float* x  = (const float*)d_in[0];
    const float* W  = (const float*)d_in[1];
    const float* b  = (const float*)d_in[2];
    const int*   ei = (const int*)d_in[3];
    float* out = (float*)d_out;

    char* ws = (char*)d_ws;
    int*            deg    = (int*)(ws + OFF_DEG);
    float*          dinv   = (float*)(ws + OFF_DINV);
    int*            flag   = (int*)(ws + OFF_FLAG);
    int*            seg    = (int*)(ws + OFF_SEG);
    int*            rowptr = (int*)(ws + OFF_ROWPTR);
    int*            csr    = (int*)(ws + OFF_CSR);
    unsigned short* wtg    = (unsigned short*)(ws + OFF_WT);
    unsigned short* gb     = (unsigned short*)(ws + OFF_G);

    hipMemsetAsync(deg, 0, NN * sizeof(int), stream);
    k_detect<<<1, 256, 0, stream>>>(ei, flag);
    k_deg<<<(NE + 255) / 256, 256, 0, stream>>>(ei, flag, deg);
    k_dinv<<<(NN + 255) / 256, 256, 0, stream>>>(deg, dinv);

    k_scan1<<<SCAN_T / 256, 256, 0, stream>>>(deg, seg);
    k_scan2<<<1, SCAN_T, 0, stream>>>(seg);
    k_scan3<<<SCAN_T / 256, 256, 0, stream>>>(deg, seg, rowptr);
    k_fill<<<(NE + 255) / 256, 256, 0, stream>>>(ei, flag, rowptr, deg, csr);

    k_wprep<<<(F * F + 255) / 256, 256, 0, stream>>>(W, wtg);

    static const int lds_bytes = 2 * 128 * XS_LD * 2;  // 69632
    hipFuncSetAttribute(reinterpret_cast<const void*>(k_gemm),
                        hipFuncAttributeMaxDynamicSharedMemorySize, lds_bytes);
    k_gemm<<<(NN + 127) / 128, 256, lds_bytes, stream>>>(x, wtg, dinv, gb);

    k_gather<<<(NN + 3) / 4, 256, 0, stream>>>(rowptr, csr, gb, dinv, b, out);
}

// Round 5
// 301.705 us; speedup vs baseline: 2.5011x; 1.0328x over previous
//
#include <hip/hip_runtime.h>

#define NN 100000
#define NE 600000
#define F  128

// workspace layout (bytes)
#define OFF_DEG    0              // int[NN]            (destroyed by k_fill)
#define OFF_DINV   (512*1024)     // float[NN]
#define OFF_FLAG   (960*1024)     // int[1]
#define OFF_SEG    (964*1024)     // int[1024]
#define OFF_ROWPTR (1024*1024)    // int[NN+1]
#define OFF_CSR    (1536*1024)    // int[NE]  (2.4 MB)
#define OFF_WT     (3968*1024)    // ushort[F*F]  W^T in bf16 (32 KB)
#define OFF_G      (4096*1024)    // ushort[NN*F] g in bf16 (25.6 MB)

#define SCAN_T 1024
#define SCAN_CH 98   // 1024*98 >= 100000

typedef __attribute__((ext_vector_type(8))) short bf16x8;
typedef __attribute__((ext_vector_type(16))) float f32x16;

__device__ inline unsigned short f2b(float f) {  // fp32 -> bf16 RNE
    unsigned int u = __builtin_bit_cast(unsigned int, f);
    u += 0x7fffu + ((u >> 16) & 1u);
    return (unsigned short)(u >> 16);
}
__device__ inline float b_lo(unsigned int v) {  // low bf16 -> fp32
    return __builtin_bit_cast(float, v << 16);
}
__device__ inline float b_hi(unsigned int v) {  // high bf16 -> fp32
    return __builtin_bit_cast(float, v & 0xffff0000u);
}

// ---------------------------------------------------------------------------
__global__ void k_detect(const int* __restrict__ ei, int* __restrict__ flag) {
    __shared__ int cnt;
    if (threadIdx.x == 0) cnt = 0;
    __syncthreads();
    int v = ei[2 * threadIdx.x + 1];
    if (v == 0) atomicAdd(&cnt, 1);
    __syncthreads();
    if (threadIdx.x == 0) *flag = (cnt > 128) ? 1 : 0;
}

__global__ __launch_bounds__(256) void k_deg(const int* __restrict__ ei,
                                             const int* __restrict__ flag,
                                             int* __restrict__ deg) {
    int e = blockIdx.x * 256 + threadIdx.x;
    if (e < NE) {
        int f = *flag;
        int dst = ei[(NE + e) << f];
        atomicAdd(&deg[dst], 1);
    }
}

// ---------------------------------------------------------------------------
__global__ __launch_bounds__(256) void k_scan1(const int* __restrict__ deg,
                                               int* __restrict__ seg) {
    int t = blockIdx.x * 256 + threadIdx.x;
    if (t >= SCAN_T) return;
    int lo = t * SCAN_CH, hi = min(lo + SCAN_CH, NN);
    int s = 0;
    for (int i = lo; i < hi; ++i) s += deg[i];
    seg[t] = s;
}

__global__ __launch_bounds__(SCAN_T) void k_scan2(int* __restrict__ seg) {
    __shared__ int s[SCAN_T];
    int t = threadIdx.x;
    int v = seg[t];
    s[t] = v;
    __syncthreads();
    for (int off = 1; off < SCAN_T; off <<= 1) {
        int u = (t >= off) ? s[t - off] : 0;
        __syncthreads();
        s[t] += u;
        __syncthreads();
    }
    seg[t] = s[t] - v;  // exclusive
}

// also computes dinv (fused former k_dinv — one fewer launch + deg pass)
__global__ __launch_bounds__(256) void k_scan3(const int* __restrict__ deg,
                                               const int* __restrict__ seg,
                                               int* __restrict__ rowptr,
                                               float* __restrict__ dinv) {
    int t = blockIdx.x * 256 + threadIdx.x;
    if (t >= SCAN_T) return;
    int lo = t * SCAN_CH, hi = min(lo + SCAN_CH, NN);
    int base = seg[t];
    for (int i = lo; i < hi; ++i) {
        int d = deg[i];
        rowptr[i] = base;
        base += d;
        dinv[i] = rsqrtf((float)(d + 1));  // +1 self-loop
    }
    if (t == 0) rowptr[NN] = NE;
}

// ---------------------------------------------------------------------------
__global__ __launch_bounds__(256) void k_fill(const int* __restrict__ ei,
                                              const int* __restrict__ flag,
                                              const int* __restrict__ rowptr,
                                              int* __restrict__ deg,
                                              int* __restrict__ csr) {
    int e = blockIdx.x * 256 + threadIdx.x;
    if (e >= NE) return;
    int f = *flag;
    int src = ei[e << f];
    int dst = ei[(NE + e) << f];
    int old = atomicSub(&deg[dst], 1);
    csr[rowptr[dst] + old - 1] = src;
}

// ---------------------------------------------------------------------------
// Wt[n][k] = bf16(W[k][n])
__global__ __launch_bounds__(256) void k_wprep(const float* __restrict__ W,
                                               unsigned short* __restrict__ wtg) {
    int idx = blockIdx.x * 256 + threadIdx.x;
    if (idx >= F * F) return;
    int k = idx >> 7, n = idx & 127;
    wtg[n * F + k] = f2b(W[k * F + n]);
}

// ---------------------------------------------------------------------------
// g = bf16( (x @ W) * dinv[row] )  via bf16 MFMA 32x32x16.
#define XS_LD 136
__global__ __launch_bounds__(256) void k_gemm(const float* __restrict__ x,
                                              const unsigned short* __restrict__ wtg,
                                              const float* __restrict__ dinv,
                                              unsigned short* __restrict__ gb) {
    extern __shared__ unsigned short smem[];
    unsigned short* xs = smem;                 // [128][136]
    unsigned short* wt = smem + 128 * XS_LD;   // [128][136]

    const int tid  = threadIdx.x;
    const int row0 = blockIdx.x * 128;

    for (int i = tid; i < 128 * 32; i += 256) {
        int r = i >> 5, kq = i & 31;
        int row = row0 + r;
        float4 v = make_float4(0.f, 0.f, 0.f, 0.f);
        if (row < NN) v = *(const float4*)(x + (long)row * F + 4 * kq);
        ushort4 h;
        h.x = f2b(v.x); h.y = f2b(v.y); h.z = f2b(v.z); h.w = f2b(v.w);
        *(ushort4*)(xs + r * XS_LD + 4 * kq) = h;
    }
    for (int i = tid; i < 128 * 16; i += 256) {
        int r = i >> 4, seg = i & 15;
        *(uint4*)(wt + r * XS_LD + seg * 8) = *(const uint4*)(wtg + r * F + seg * 8);
    }
    __syncthreads();

    const int w    = tid >> 6;
    const int lane = tid & 63;
    const int m    = lane & 31;
    const int half = lane >> 5;

    f32x16 acc[4];
#pragma unroll
    for (int t = 0; t < 4; ++t)
#pragma unroll
        for (int j = 0; j < 16; ++j) acc[t][j] = 0.f;

    const unsigned short* xrow = xs + (32 * w + m) * XS_LD;
#pragma unroll
    for (int kc = 0; kc < 8; ++kc) {
        bf16x8 a = *(const bf16x8*)(xrow + kc * 16 + half * 8);
#pragma unroll
        for (int nt = 0; nt < 4; ++nt) {
            bf16x8 bfr = *(const bf16x8*)(wt + (nt * 32 + m) * XS_LD + kc * 16 + half * 8);
            acc[nt] = __builtin_amdgcn_mfma_f32_32x32x16_bf16(a, bfr, acc[nt], 0, 0, 0);
        }
    }

    const int rbase = 32 * w + 4 * half;
    float dv[16];
#pragma unroll
    for (int reg = 0; reg < 16; ++reg) {
        int grow = row0 + rbase + (reg & 3) + 8 * (reg >> 2);
        dv[reg] = (grow < NN) ? dinv[grow] : 0.f;
    }
#pragma unroll
    for (int nt = 0; nt < 4; ++nt) {
#pragma unroll
        for (int reg = 0; reg < 16; ++reg) {
            int grow = row0 + rbase + (reg & 3) + 8 * (reg >> 2);
            if (grow < NN)
                gb[(long)grow * F + nt * 32 + m] = f2b(acc[nt][reg] * dv[reg]);
        }
    }
}

// ---------------------------------------------------------------------------
// One wave per node, 4 groups of 16 lanes; each group covers the full 128-col
// row with uint4 (8 bf16) per lane and walks edges p0+grp, p0+grp+4, ...
// (2-deep unroll -> up to 8 row-gathers in flight per wave; R4 version had 1,
// measured latency-bound at 23% HBM). Butterfly shfl_xor(16,32) combines
// groups; group 0 applies dinv/bias/relu and stores.
__global__ __launch_bounds__(256) void k_gather(const int* __restrict__ rowptr,
                                                const int* __restrict__ csr,
                                                const unsigned short* __restrict__ gb,
                                                const float* __restrict__ dinv,
                                                const float* __restrict__ b,
                                                float* __restrict__ out) {
    int n = blockIdx.x * 4 + (threadIdx.x >> 6);
    if (n >= NN) return;
    const int lane = threadIdx.x & 63;
    const int l16  = lane & 15;
    const int grp  = lane >> 4;

    float a[8];
    if (grp == 0) {  // self-loop row
        uint4 v = *(const uint4*)(gb + (long)n * F + l16 * 8);
        a[0] = b_lo(v.x); a[1] = b_hi(v.x); a[2] = b_lo(v.y); a[3] = b_hi(v.y);
        a[4] = b_lo(v.z); a[5] = b_hi(v.z); a[6] = b_lo(v.w); a[7] = b_hi(v.w);
    } else {
#pragma unroll
        for (int j = 0; j < 8; ++j) a[j] = 0.f;
    }

    const int p1 = rowptr[n + 1];
    int p = rowptr[n] + grp;
    for (; p + 4 < p1; p += 8) {
        int s0 = csr[p];
        int s1 = csr[p + 4];
        uint4 v0 = *(const uint4*)(gb + (long)s0 * F + l16 * 8);
        uint4 v1 = *(const uint4*)(gb + (long)s1 * F + l16 * 8);
        a[0] += b_lo(v0.x); a[1] += b_hi(v0.x); a[2] += b_lo(v0.y); a[3] += b_hi(v0.y);
        a[4] += b_lo(v0.z); a[5] += b_hi(v0.z); a[6] += b_lo(v0.w); a[7] += b_hi(v0.w);
        a[0] += b_lo(v1.x); a[1] += b_hi(v1.x); a[2] += b_lo(v1.y); a[3] += b_hi(v1.y);
        a[4] += b_lo(v1.z); a[5] += b_hi(v1.z); a[6] += b_lo(v1.w); a[7] += b_hi(v1.w);
    }
    if (p < p1) {
        int s0 = csr[p];
        uint4 v0 = *(const uint4*)(gb + (long)s0 * F + l16 * 8);
        a[0] += b_lo(v0.x); a[1] += b_hi(v0.x); a[2] += b_lo(v0.y); a[3] += b_hi(v0.y);
        a[4] += b_lo(v0.z); a[5] += b_hi(v0.z); a[6] += b_lo(v0.w); a[7] += b_hi(v0.w);
    }

#pragma unroll
    for (int j = 0; j < 8; ++j) {
        a[j] += __shfl_xor(a[j], 16);
        a[j] += __shfl_xor(a[j], 32);
    }

    if (grp == 0) {
        float dv = dinv[n];
        float4 b0 = *(const float4*)(b + l16 * 8);
        float4 b1 = *(const float4*)(b + l16 * 8 + 4);
        float4 o0, o1;
        o0.x = fmaxf(a[0] * dv + b0.x, 0.f);
        o0.y = fmaxf(a[1] * dv + b0.y, 0.f);
        o0.z = fmaxf(a[2] * dv + b0.z, 0.f);
        o0.w = fmaxf(a[3] * dv + b0.w, 0.f);
        o1.x = fmaxf(a[4] * dv + b1.x, 0.f);
        o1.y = fmaxf(a[5] * dv + b1.y, 0.f);
        o1.z = fmaxf(a[6] * dv + b1.z, 0.f);
        o1.w = fmaxf(a[7] * dv + b1.w, 0.f);
        long base = (long)n * F + l16 * 8;
        *(float4*)(out + base)     = o0;
        *(float4*)(out + base + 4) = o1;
    }
}

// ---------------------------------------------------------------------------
extern "C" void kernel_launch(void* const* d_in, const int* in_sizes, int n_in,
                              void* d_out, int out_size, void* d_ws, size_t ws_size,
                              hipStream_t stream) {
    const float* x  = (const float*)d_in[0];
    const float* W  = (const float*)d_in[1];
    const float* b  = (const float*)d_in[2];
    const int*   ei = (const int*)d_in[3];
    float* out = (float*)d_out;

    char* ws = (char*)d_ws;
    int*            deg    = (int*)(ws + OFF_DEG);
    float*          dinv   = (float*)(ws + OFF_DINV);
    int*            flag   = (int*)(ws + OFF_FLAG);
    int*            seg    = (int*)(ws + OFF_SEG);
    int*            rowptr = (int*)(ws + OFF_ROWPTR);
    int*            csr    = (int*)(ws + OFF_CSR);
    unsigned short* wtg    = (unsigned short*)(ws + OFF_WT);
    unsigned short* gb     = (unsigned short*)(ws + OFF_G);

    hipMemsetAsync(deg, 0, NN * sizeof(int), stream);
    k_detect<<<1, 256, 0, stream>>>(ei, flag);
    k_deg<<<(NE + 255) / 256, 256, 0, stream>>>(ei, flag, deg);

    k_scan1<<<SCAN_T / 256, 256, 0, stream>>>(deg, seg);
    k_scan2<<<1, SCAN_T, 0, stream>>>(seg);
    k_scan3<<<SCAN_T / 256, 256, 0, stream>>>(deg, seg, rowptr, dinv);
    k_fill<<<(NE + 255) / 256, 256, 0, stream>>>(ei, flag, rowptr, deg, csr);

    k_wprep<<<(F * F + 255) / 256, 256, 0, stream>>>(W, wtg);

    static const int lds_bytes = 2 * 128 * XS_LD * 2;  // 69632
    hipFuncSetAttribute(reinterpret_cast<const void*>(k_gemm),
                        hipFuncAttributeMaxDynamicSharedMemorySize, lds_bytes);
    k_gemm<<<(NN + 127) / 128, 256, lds_bytes, stream>>>(x, wtg, dinv, gb);

    k_gather<<<(NN + 3) / 4, 256, 0, stream>>>(rowptr, csr, gb, dinv, b, out);
}

// Round 6
// 243.632 us; speedup vs baseline: 3.0973x; 1.2384x over previous
//
#include <hip/hip_runtime.h>

#define NN 100000
#define NE 600000
#define F  128

#define NBLK ((NN + 255) / 256)   // 391 blocks for per-element kernels

// workspace layout (bytes)
#define OFF_DEG    0              // int[NN]            (destroyed by k_fill)
#define OFF_DINV   (512*1024)     // float[NN]
#define OFF_FLAG   (960*1024)     // int[1]
#define OFF_SEG    (964*1024)     // int[NBLK]
#define OFF_ROWPTR (1024*1024)    // int[NN+1]
#define OFF_CSR    (1536*1024)    // int[NE]  (2.4 MB)
#define OFF_WT     (3968*1024)    // ushort[F*F]  W^T in bf16 (32 KB)
#define OFF_G      (4096*1024)    // ushort[NN*F] g in bf16 (25.6 MB)

typedef __attribute__((ext_vector_type(8))) short bf16x8;
typedef __attribute__((ext_vector_type(16))) float f32x16;

__device__ inline unsigned short f2b(float f) {  // fp32 -> bf16 RNE
    unsigned int u = __builtin_bit_cast(unsigned int, f);
    u += 0x7fffu + ((u >> 16) & 1u);
    return (unsigned short)(u >> 16);
}
__device__ inline float b_lo(unsigned int v) {  // low bf16 -> fp32
    return __builtin_bit_cast(float, v << 16);
}
__device__ inline float b_hi(unsigned int v) {  // high bf16 -> fp32
    return __builtin_bit_cast(float, v & 0xffff0000u);
}

// ---------------------------------------------------------------------------
__global__ void k_detect(const int* __restrict__ ei, int* __restrict__ flag) {
    __shared__ int cnt;
    if (threadIdx.x == 0) cnt = 0;
    __syncthreads();
    int v = ei[2 * threadIdx.x + 1];
    if (v == 0) atomicAdd(&cnt, 1);
    __syncthreads();
    if (threadIdx.x == 0) *flag = (cnt > 128) ? 1 : 0;
}

__global__ __launch_bounds__(256) void k_deg(const int* __restrict__ ei,
                                             const int* __restrict__ flag,
                                             int* __restrict__ deg) {
    int e = blockIdx.x * 256 + threadIdx.x;
    if (e < NE) {
        int f = *flag;
        int dst = ei[(NE + e) << f];
        atomicAdd(&deg[dst], 1);
    }
}

// ---------------------------------------------------------------------------
// Fully-parallel prefix sum (R5's 1024-thread sequential scan measured 58 µs
// at 0.16% occupancy — 4 blocks on a 256-CU chip).
// A: per-block exclusive scan of deg -> rowptr (local), block sums -> seg;
//    dinv fused (reads deg anyway).
__global__ __launch_bounds__(256) void k_scanA(const int* __restrict__ deg,
                                               int* __restrict__ rowptr,
                                               float* __restrict__ dinv,
                                               int* __restrict__ seg) {
    int i = blockIdx.x * 256 + threadIdx.x;
    int lane = threadIdx.x & 63, w = threadIdx.x >> 6;
    int v = (i < NN) ? deg[i] : 0;
    int s = v;
#pragma unroll
    for (int off = 1; off < 64; off <<= 1) {
        int u = __shfl_up(s, off);
        if (lane >= off) s += u;
    }
    __shared__ int wsum[4];
    if (lane == 63) wsum[w] = s;
    __syncthreads();
    int base = 0;
#pragma unroll
    for (int j = 0; j < 4; ++j)
        if (j < w) base += wsum[j];
    int exc = base + s - v;  // block-local exclusive
    if (i < NN) {
        rowptr[i] = exc;
        dinv[i] = rsqrtf((float)(v + 1));  // +1 self-loop
    }
    if (threadIdx.x == 255) seg[blockIdx.x] = exc + v;  // block total
}

// B: one 512-thread block scans the NBLK block sums (exclusive).
__global__ __launch_bounds__(512) void k_scanB(int* __restrict__ seg) {
    __shared__ int s[512];
    int t = threadIdx.x;
    int v = (t < NBLK) ? seg[t] : 0;
    s[t] = v;
    __syncthreads();
    for (int off = 1; off < 512; off <<= 1) {
        int u = (t >= off) ? s[t - off] : 0;
        __syncthreads();
        s[t] += u;
        __syncthreads();
    }
    if (t < NBLK) seg[t] = s[t] - v;  // exclusive
}

// C: add block offsets.
__global__ __launch_bounds__(256) void k_scanC(int* __restrict__ rowptr,
                                               const int* __restrict__ seg) {
    int i = blockIdx.x * 256 + threadIdx.x;
    if (i < NN) rowptr[i] += seg[blockIdx.x];
    if (i == 0) rowptr[NN] = NE;
}

// ---------------------------------------------------------------------------
__global__ __launch_bounds__(256) void k_fill(const int* __restrict__ ei,
                                              const int* __restrict__ flag,
                                              const int* __restrict__ rowptr,
                                              int* __restrict__ deg,
                                              int* __restrict__ csr) {
    int e = blockIdx.x * 256 + threadIdx.x;
    if (e >= NE) return;
    int f = *flag;
    int src = ei[e << f];
    int dst = ei[(NE + e) << f];
    int old = atomicSub(&deg[dst], 1);
    csr[rowptr[dst] + old - 1] = src;
}

// ---------------------------------------------------------------------------
// Wt[n][k] = bf16(W[k][n])
__global__ __launch_bounds__(256) void k_wprep(const float* __restrict__ W,
                                               unsigned short* __restrict__ wtg) {
    int idx = blockIdx.x * 256 + threadIdx.x;
    if (idx >= F * F) return;
    int k = idx >> 7, n = idx & 127;
    wtg[n * F + k] = f2b(W[k * F + n]);
}

// ---------------------------------------------------------------------------
// g = bf16( (x @ W) * dinv[row] )  via bf16 MFMA 32x32x16.
#define XS_LD 136
__global__ __launch_bounds__(256) void k_gemm(const float* __restrict__ x,
                                              const unsigned short* __restrict__ wtg,
                                              const float* __restrict__ dinv,
                                              unsigned short* __restrict__ gb) {
    extern __shared__ unsigned short smem[];
    unsigned short* xs = smem;                 // [128][136]
    unsigned short* wt = smem + 128 * XS_LD;   // [128][136]

    const int tid  = threadIdx.x;
    const int row0 = blockIdx.x * 128;

    for (int i = tid; i < 128 * 32; i += 256) {
        int r = i >> 5, kq = i & 31;
        int row = row0 + r;
        float4 v = make_float4(0.f, 0.f, 0.f, 0.f);
        if (row < NN) v = *(const float4*)(x + (long)row * F + 4 * kq);
        ushort4 h;
        h.x = f2b(v.x); h.y = f2b(v.y); h.z = f2b(v.z); h.w = f2b(v.w);
        *(ushort4*)(xs + r * XS_LD + 4 * kq) = h;
    }
    for (int i = tid; i < 128 * 16; i += 256) {
        int r = i >> 4, seg = i & 15;
        *(uint4*)(wt + r * XS_LD + seg * 8) = *(const uint4*)(wtg + r * F + seg * 8);
    }
    __syncthreads();

    const int w    = tid >> 6;
    const int lane = tid & 63;
    const int m    = lane & 31;
    const int half = lane >> 5;

    f32x16 acc[4];
#pragma unroll
    for (int t = 0; t < 4; ++t)
#pragma unroll
        for (int j = 0; j < 16; ++j) acc[t][j] = 0.f;

    const unsigned short* xrow = xs + (32 * w + m) * XS_LD;
#pragma unroll
    for (int kc = 0; kc < 8; ++kc) {
        bf16x8 a = *(const bf16x8*)(xrow + kc * 16 + half * 8);
#pragma unroll
        for (int nt = 0; nt < 4; ++nt) {
            bf16x8 bfr = *(const bf16x8*)(wt + (nt * 32 + m) * XS_LD + kc * 16 + half * 8);
            acc[nt] = __builtin_amdgcn_mfma_f32_32x32x16_bf16(a, bfr, acc[nt], 0, 0, 0);
        }
    }

    const int rbase = 32 * w + 4 * half;
    float dv[16];
#pragma unroll
    for (int reg = 0; reg < 16; ++reg) {
        int grow = row0 + rbase + (reg & 3) + 8 * (reg >> 2);
        dv[reg] = (grow < NN) ? dinv[grow] : 0.f;
    }
#pragma unroll
    for (int nt = 0; nt < 4; ++nt) {
#pragma unroll
        for (int reg = 0; reg < 16; ++reg) {
            int grow = row0 + rbase + (reg & 3) + 8 * (reg >> 2);
            if (grow < NN)
                gb[(long)grow * F + nt * 32 + m] = f2b(acc[nt][reg] * dv[reg]);
        }
    }
}

// ---------------------------------------------------------------------------
// One wave per node, 4 groups of 16 lanes; each group covers the full 128-col
// row with uint4 (8 bf16) per lane and walks edges p0+grp, p0+grp+4, ...
// Butterfly shfl_xor(16,32) combines groups; group 0 stores.
__global__ __launch_bounds__(256) void k_gather(const int* __restrict__ rowptr,
                                                const int* __restrict__ csr,
                                                const unsigned short* __restrict__ gb,
                                                const float* __restrict__ dinv,
                                                const float* __restrict__ b,
                                                float* __restrict__ out) {
    int n = blockIdx.x * 4 + (threadIdx.x >> 6);
    if (n >= NN) return;
    const int lane = threadIdx.x & 63;
    const int l16  = lane & 15;
    const int grp  = lane >> 4;

    float a[8];
    if (grp == 0) {  // self-loop row
        uint4 v = *(const uint4*)(gb + (long)n * F + l16 * 8);
        a[0] = b_lo(v.x); a[1] = b_hi(v.x); a[2] = b_lo(v.y); a[3] = b_hi(v.y);
        a[4] = b_lo(v.z); a[5] = b_hi(v.z); a[6] = b_lo(v.w); a[7] = b_hi(v.w);
    } else {
#pragma unroll
        for (int j = 0; j < 8; ++j) a[j] = 0.f;
    }

    const int p1 = rowptr[n + 1];
    int p = rowptr[n] + grp;
    for (; p + 4 < p1; p += 8) {
        int s0 = csr[p];
        int s1 = csr[p + 4];
        uint4 v0 = *(const uint4*)(gb + (long)s0 * F + l16 * 8);
        uint4 v1 = *(const uint4*)(gb + (long)s1 * F + l16 * 8);
        a[0] += b_lo(v0.x); a[1] += b_hi(v0.x); a[2] += b_lo(v0.y); a[3] += b_hi(v0.y);
        a[4] += b_lo(v0.z); a[5] += b_hi(v0.z); a[6] += b_lo(v0.w); a[7] += b_hi(v0.w);
        a[0] += b_lo(v1.x); a[1] += b_hi(v1.x); a[2] += b_lo(v1.y); a[3] += b_hi(v1.y);
        a[4] += b_lo(v1.z); a[5] += b_hi(v1.z); a[6] += b_lo(v1.w); a[7] += b_hi(v1.w);
    }
    if (p < p1) {
        int s0 = csr[p];
        uint4 v0 = *(const uint4*)(gb + (long)s0 * F + l16 * 8);
        a[0] += b_lo(v0.x); a[1] += b_hi(v0.x); a[2] += b_lo(v0.y); a[3] += b_hi(v0.y);
        a[4] += b_lo(v0.z); a[5] += b_hi(v0.z); a[6] += b_lo(v0.w); a[7] += b_hi(v0.w);
    }

#pragma unroll
    for (int j = 0; j < 8; ++j) {
        a[j] += __shfl_xor(a[j], 16);
        a[j] += __shfl_xor(a[j], 32);
    }

    if (grp == 0) {
        float dv = dinv[n];
        float4 b0 = *(const float4*)(b + l16 * 8);
        float4 b1 = *(const float4*)(b + l16 * 8 + 4);
        float4 o0, o1;
        o0.x = fmaxf(a[0] * dv + b0.x, 0.f);
        o0.y = fmaxf(a[1] * dv + b0.y, 0.f);
        o0.z = fmaxf(a[2] * dv + b0.z, 0.f);
        o0.w = fmaxf(a[3] * dv + b0.w, 0.f);
        o1.x = fmaxf(a[4] * dv + b1.x, 0.f);
        o1.y = fmaxf(a[5] * dv + b1.y, 0.f);
        o1.z = fmaxf(a[6] * dv + b1.z, 0.f);
        o1.w = fmaxf(a[7] * dv + b1.w, 0.f);
        long base = (long)n * F + l16 * 8;
        *(float4*)(out + base)     = o0;
        *(float4*)(out + base + 4) = o1;
    }
}

// ---------------------------------------------------------------------------
extern "C" void kernel_launch(void* const* d_in, const int* in_sizes, int n_in,
                              void* d_out, int out_size, void* d_ws, size_t ws_size,
                              hipStream_t stream) {
    const float* x  = (const float*)d_in[0];
    const float* W  = (const float*)d_in[1];
    const float* b  = (const float*)d_in[2];
    const int*   ei = (const int*)d_in[3];
    float* out = (float*)d_out;

    char* ws = (char*)d_ws;
    int*            deg    = (int*)(ws + OFF_DEG);
    float*          dinv   = (float*)(ws + OFF_DINV);
    int*            flag   = (int*)(ws + OFF_FLAG);
    int*            seg    = (int*)(ws + OFF_SEG);
    int*            rowptr = (int*)(ws + OFF_ROWPTR);
    int*            csr    = (int*)(ws + OFF_CSR);
    unsigned short* wtg    = (unsigned short*)(ws + OFF_WT);
    unsigned short* gb     = (unsigned short*)(ws + OFF_G);

    hipMemsetAsync(deg, 0, NN * sizeof(int), stream);
    k_detect<<<1, 256, 0, stream>>>(ei, flag);
    k_deg<<<(NE + 255) / 256, 256, 0, stream>>>(ei, flag, deg);

    k_scanA<<<NBLK, 256, 0, stream>>>(deg, rowptr, dinv, seg);
    k_scanB<<<1, 512, 0, stream>>>(seg);
    k_scanC<<<NBLK, 256, 0, stream>>>(rowptr, seg);
    k_fill<<<(NE + 255) / 256, 256, 0, stream>>>(ei, flag, rowptr, deg, csr);

    k_wprep<<<(F * F + 255) / 256, 256, 0, stream>>>(W, wtg);

    static const int lds_bytes = 2 * 128 * XS_LD * 2;  // 69632
    hipFuncSetAttribute(reinterpret_cast<const void*>(k_gemm),
                        hipFuncAttributeMaxDynamicSharedMemorySize, lds_bytes);
    k_gemm<<<(NN + 127) / 128, 256, lds_bytes, stream>>>(x, wtg, dinv, gb);

    k_gather<<<(NN + 3) / 4, 256, 0, stream>>>(rowptr, csr, gb, dinv, b, out);
}

// Round 7
// 240.711 us; speedup vs baseline: 3.1349x; 1.0121x over previous
//
#include <hip/hip_runtime.h>

#define NN 100000
#define NE 600000
#define F  128

#define NBLK ((NN + 255) / 256)   // 391 blocks for per-element kernels

// workspace layout (bytes)
#define OFF_DEG    0              // int[NN]            (destroyed by k_fill)
#define OFF_DINV   (512*1024)     // float[NN]
#define OFF_FLAG   (960*1024)     // int[1]
#define OFF_SEG    (964*1024)     // int[NBLK]
#define OFF_ROWPTR (1024*1024)    // int[NN+1]
#define OFF_CSR    (1536*1024)    // int[NE]  (2.4 MB)
#define OFF_WT     (3968*1024)    // ushort[F*F]  W^T in bf16 (32 KB)
#define OFF_G      (4096*1024)    // ushort[NN*F] g in bf16 (25.6 MB)

typedef __attribute__((ext_vector_type(8))) short bf16x8;
typedef __attribute__((ext_vector_type(16))) float f32x16;

__device__ inline unsigned short f2b(float f) {  // fp32 -> bf16 RNE
    unsigned int u = __builtin_bit_cast(unsigned int, f);
    u += 0x7fffu + ((u >> 16) & 1u);
    return (unsigned short)(u >> 16);
}
__device__ inline float b_lo(unsigned int v) {  // low bf16 -> fp32
    return __builtin_bit_cast(float, v << 16);
}
__device__ inline float b_hi(unsigned int v) {  // high bf16 -> fp32
    return __builtin_bit_cast(float, v & 0xffff0000u);
}

// ---------------------------------------------------------------------------
__global__ void k_detect(const int* __restrict__ ei, int* __restrict__ flag) {
    __shared__ int cnt;
    if (threadIdx.x == 0) cnt = 0;
    __syncthreads();
    int v = ei[2 * threadIdx.x + 1];
    if (v == 0) atomicAdd(&cnt, 1);
    __syncthreads();
    if (threadIdx.x == 0) *flag = (cnt > 128) ? 1 : 0;
}

__global__ __launch_bounds__(256) void k_deg(const int* __restrict__ ei,
                                             const int* __restrict__ flag,
                                             int* __restrict__ deg) {
    int e = blockIdx.x * 256 + threadIdx.x;
    if (e < NE) {
        int f = *flag;
        int dst = ei[(NE + e) << f];
        atomicAdd(&deg[dst], 1);
    }
}

// ---------------------------------------------------------------------------
// Fully-parallel prefix sum. A: per-block scan, dinv fused.
__global__ __launch_bounds__(256) void k_scanA(const int* __restrict__ deg,
                                               int* __restrict__ rowptr,
                                               float* __restrict__ dinv,
                                               int* __restrict__ seg) {
    int i = blockIdx.x * 256 + threadIdx.x;
    int lane = threadIdx.x & 63, w = threadIdx.x >> 6;
    int v = (i < NN) ? deg[i] : 0;
    int s = v;
#pragma unroll
    for (int off = 1; off < 64; off <<= 1) {
        int u = __shfl_up(s, off);
        if (lane >= off) s += u;
    }
    __shared__ int wsum[4];
    if (lane == 63) wsum[w] = s;
    __syncthreads();
    int base = 0;
#pragma unroll
    for (int j = 0; j < 4; ++j)
        if (j < w) base += wsum[j];
    int exc = base + s - v;  // block-local exclusive
    if (i < NN) {
        rowptr[i] = exc;
        dinv[i] = rsqrtf((float)(v + 1));  // +1 self-loop
    }
    if (threadIdx.x == 255) seg[blockIdx.x] = exc + v;  // block total
}

// B: one 512-thread block scans the NBLK block sums (exclusive).
__global__ __launch_bounds__(512) void k_scanB(int* __restrict__ seg) {
    __shared__ int s[512];
    int t = threadIdx.x;
    int v = (t < NBLK) ? seg[t] : 0;
    s[t] = v;
    __syncthreads();
    for (int off = 1; off < 512; off <<= 1) {
        int u = (t >= off) ? s[t - off] : 0;
        __syncthreads();
        s[t] += u;
        __syncthreads();
    }
    if (t < NBLK) seg[t] = s[t] - v;  // exclusive
}

// C: add block offsets.
__global__ __launch_bounds__(256) void k_scanC(int* __restrict__ rowptr,
                                               const int* __restrict__ seg) {
    int i = blockIdx.x * 256 + threadIdx.x;
    if (i < NN) rowptr[i] += seg[blockIdx.x];
    if (i == 0) rowptr[NN] = NE;
}

// ---------------------------------------------------------------------------
__global__ __launch_bounds__(256) void k_fill(const int* __restrict__ ei,
                                              const int* __restrict__ flag,
                                              const int* __restrict__ rowptr,
                                              int* __restrict__ deg,
                                              int* __restrict__ csr) {
    int e = blockIdx.x * 256 + threadIdx.x;
    if (e >= NE) return;
    int f = *flag;
    int src = ei[e << f];
    int dst = ei[(NE + e) << f];
    int old = atomicSub(&deg[dst], 1);
    csr[rowptr[dst] + old - 1] = src;
}

// ---------------------------------------------------------------------------
// Wt[n][k] = bf16(W[k][n])
__global__ __launch_bounds__(256) void k_wprep(const float* __restrict__ W,
                                               unsigned short* __restrict__ wtg) {
    int idx = blockIdx.x * 256 + threadIdx.x;
    if (idx >= F * F) return;
    int k = idx >> 7, n = idx & 127;
    wtg[n * F + k] = f2b(W[k * F + n]);
}

// ---------------------------------------------------------------------------
// g = bf16( (x @ W) * dinv[row] ) via bf16 MFMA 32x32x16 — NO LDS, no barriers.
// R6 LDS version measured 14% occupancy (69.6 KB LDS -> 2 blocks/CU) and was
// latency-bound (MfmaUtil 2.4%, VALUBusy 8.6%, HBM 14%). A-fragment for
// 32x32x16 (m=lane&31, k=half*8+j) is 8 contiguous floats of one x row ->
// load direct from global + cvt; B-fragment is 16 contiguous bytes of a Wt
// row (32 KB table, L2-resident). All loads independent; occupancy now
// VGPR-bound only.
__global__ __launch_bounds__(256) void k_gemm(const float* __restrict__ x,
                                              const unsigned short* __restrict__ wtg,
                                              const float* __restrict__ dinv,
                                              unsigned short* __restrict__ gb) {
    const int tid  = threadIdx.x;
    const int w    = tid >> 6;
    const int lane = tid & 63;
    const int m    = lane & 31;
    const int half = lane >> 5;
    const int row0 = blockIdx.x * 128;

    const int arow = min(row0 + 32 * w + m, NN - 1);  // OOB rows clamped; their
                                                      // C rows are never stored
    const float*          xr = x   + (long)arow * F + half * 8;
    const unsigned short* wr = wtg + m * F + half * 8;

    f32x16 acc[4];
#pragma unroll
    for (int t = 0; t < 4; ++t)
#pragma unroll
        for (int j = 0; j < 16; ++j) acc[t][j] = 0.f;

#pragma unroll
    for (int kc = 0; kc < 8; ++kc) {
        float4 a0 = *(const float4*)(xr + kc * 16);
        float4 a1 = *(const float4*)(xr + kc * 16 + 4);
        bf16x8 a;
        a[0] = (short)f2b(a0.x); a[1] = (short)f2b(a0.y);
        a[2] = (short)f2b(a0.z); a[3] = (short)f2b(a0.w);
        a[4] = (short)f2b(a1.x); a[5] = (short)f2b(a1.y);
        a[6] = (short)f2b(a1.z); a[7] = (short)f2b(a1.w);
#pragma unroll
        for (int nt = 0; nt < 4; ++nt) {
            bf16x8 bfr = *(const bf16x8*)(wr + nt * 32 * F + kc * 16);
            acc[nt] = __builtin_amdgcn_mfma_f32_32x32x16_bf16(a, bfr, acc[nt], 0, 0, 0);
        }
    }

    // epilogue: C/D row = (reg&3)+8*(reg>>2)+4*half, col = m
    const int rbase = 32 * w + 4 * half;
    float dv[16];
#pragma unroll
    for (int reg = 0; reg < 16; ++reg) {
        int grow = row0 + rbase + (reg & 3) + 8 * (reg >> 2);
        dv[reg] = (grow < NN) ? dinv[grow] : 0.f;
    }
#pragma unroll
    for (int nt = 0; nt < 4; ++nt) {
#pragma unroll
        for (int reg = 0; reg < 16; ++reg) {
            int grow = row0 + rbase + (reg & 3) + 8 * (reg >> 2);
            if (grow < NN)
                gb[(long)grow * F + nt * 32 + m] = f2b(acc[nt][reg] * dv[reg]);
        }
    }
}

// ---------------------------------------------------------------------------
// One wave per node, 4 groups of 16 lanes; each group covers the full 128-col
// row with uint4 (8 bf16) per lane and walks edges p0+grp, p0+grp+4, ...
// Butterfly shfl_xor(16,32) combines groups; group 0 stores.
__global__ __launch_bounds__(256) void k_gather(const int* __restrict__ rowptr,
                                                const int* __restrict__ csr,
                                                const unsigned short* __restrict__ gb,
                                                const float* __restrict__ dinv,
                                                const float* __restrict__ b,
                                                float* __restrict__ out) {
    int n = blockIdx.x * 4 + (threadIdx.x >> 6);
    if (n >= NN) return;
    const int lane = threadIdx.x & 63;
    const int l16  = lane & 15;
    const int grp  = lane >> 4;

    float a[8];
    if (grp == 0) {  // self-loop row
        uint4 v = *(const uint4*)(gb + (long)n * F + l16 * 8);
        a[0] = b_lo(v.x); a[1] = b_hi(v.x); a[2] = b_lo(v.y); a[3] = b_hi(v.y);
        a[4] = b_lo(v.z); a[5] = b_hi(v.z); a[6] = b_lo(v.w); a[7] = b_hi(v.w);
    } else {
#pragma unroll
        for (int j = 0; j < 8; ++j) a[j] = 0.f;
    }

    const int p1 = rowptr[n + 1];
    int p = rowptr[n] + grp;
    for (; p + 4 < p1; p += 8) {
        int s0 = csr[p];
        int s1 = csr[p + 4];
        uint4 v0 = *(const uint4*)(gb + (long)s0 * F + l16 * 8);
        uint4 v1 = *(const uint4*)(gb + (long)s1 * F + l16 * 8);
        a[0] += b_lo(v0.x); a[1] += b_hi(v0.x); a[2] += b_lo(v0.y); a[3] += b_hi(v0.y);
        a[4] += b_lo(v0.z); a[5] += b_hi(v0.z); a[6] += b_lo(v0.w); a[7] += b_hi(v0.w);
        a[0] += b_lo(v1.x); a[1] += b_hi(v1.x); a[2] += b_lo(v1.y); a[3] += b_hi(v1.y);
        a[4] += b_lo(v1.z); a[5] += b_hi(v1.z); a[6] += b_lo(v1.w); a[7] += b_hi(v1.w);
    }
    if (p < p1) {
        int s0 = csr[p];
        uint4 v0 = *(const uint4*)(gb + (long)s0 * F + l16 * 8);
        a[0] += b_lo(v0.x); a[1] += b_hi(v0.x); a[2] += b_lo(v0.y); a[3] += b_hi(v0.y);
        a[4] += b_lo(v0.z); a[5] += b_hi(v0.z); a[6] += b_lo(v0.w); a[7] += b_hi(v0.w);
    }

#pragma unroll
    for (int j = 0; j < 8; ++j) {
        a[j] += __shfl_xor(a[j], 16);
        a[j] += __shfl_xor(a[j], 32);
    }

    if (grp == 0) {
        float dv = dinv[n];
        float4 b0 = *(const float4*)(b + l16 * 8);
        float4 b1 = *(const float4*)(b + l16 * 8 + 4);
        float4 o0, o1;
        o0.x = fmaxf(a[0] * dv + b0.x, 0.f);
        o0.y = fmaxf(a[1] * dv + b0.y, 0.f);
        o0.z = fmaxf(a[2] * dv + b0.z, 0.f);
        o0.w = fmaxf(a[3] * dv + b0.w, 0.f);
        o1.x = fmaxf(a[4] * dv + b1.x, 0.f);
        o1.y = fmaxf(a[5] * dv + b1.y, 0.f);
        o1.z = fmaxf(a[6] * dv + b1.z, 0.f);
        o1.w = fmaxf(a[7] * dv + b1.w, 0.f);
        long base = (long)n * F + l16 * 8;
        *(float4*)(out + base)     = o0;
        *(float4*)(out + base + 4) = o1;
    }
}

// ---------------------------------------------------------------------------
extern "C" void kernel_launch(void* const* d_in, const int* in_sizes, int n_in,
                              void* d_out, int out_size, void* d_ws, size_t ws_size,
                              hipStream_t stream) {
    const float* x  = (const float*)d_in[0];
    const float* W  = (const float*)d_in[1];
    const float* b  = (const float*)d_in[2];
    const int*   ei = (const int*)d_in[3];
    float* out = (float*)d_out;

    char* ws = (char*)d_ws;
    int*            deg    = (int*)(ws + OFF_DEG);
    float*          dinv   = (float*)(ws + OFF_DINV);
    int*            flag   = (int*)(ws + OFF_FLAG);
    int*            seg    = (int*)(ws + OFF_SEG);
    int*            rowptr = (int*)(ws + OFF_ROWPTR);
    int*            csr    = (int*)(ws + OFF_CSR);
    unsigned short* wtg    = (unsigned short*)(ws + OFF_WT);
    unsigned short* gb     = (unsigned short*)(ws + OFF_G);

    hipMemsetAsync(deg, 0, NN * sizeof(int), stream);
    k_detect<<<1, 256, 0, stream>>>(ei, flag);
    k_deg<<<(NE + 255) / 256, 256, 0, stream>>>(ei, flag, deg);

    k_scanA<<<NBLK, 256, 0, stream>>>(deg, rowptr, dinv, seg);
    k_scanB<<<1, 512, 0, stream>>>(seg);
    k_scanC<<<NBLK, 256, 0, stream>>>(rowptr, seg);
    k_fill<<<(NE + 255) / 256, 256, 0, stream>>>(ei, flag, rowptr, deg, csr);

    k_wprep<<<(F * F + 255) / 256, 256, 0, stream>>>(W, wtg);

    k_gemm<<<(NN + 127) / 128, 256, 0, stream>>>(x, wtg, dinv, gb);

    k_gather<<<(NN + 3) / 4, 256, 0, stream>>>(rowptr, csr, gb, dinv, b, out);
}